// Round 1
// baseline (547.071 us; speedup 1.0000x reference)
//
#include <hip/hip_runtime.h>
#include <hip/hip_bf16.h>

// DeformConv3d, fixed geometry:
// x: (2,32,24,24,24) f32, offset: (2,81,24,24,24) f32,
// weight: (64,32,3,3,3) f32, bias: (64,) f32 -> out: (2,64,24,24,24) f32
// stride=1, pad=1, dil=1, groups=1, deform_groups=1

constexpr int B  = 2;
constexpr int C  = 32;
constexpr int D  = 24, H = 24, W = 24;
constexpr int CO = 64;
constexpr int KN = 27;            // 3*3*3
constexpr int DO = 24, HO = 24, WO = 24;
constexpr int N  = DO * HO * WO;  // 13824
constexpr int CK = C * KN;        // 864

constexpr int NPOS    = 8;                 // output positions per block
constexpr int THREADS = 256;
constexpr int NTAP    = NPOS * KN;         // 216
constexpr int NBLK    = (B * N) / NPOS;    // 3456

__global__ __launch_bounds__(THREADS)
void deform_conv3d_kernel(const float* __restrict__ x,
                          const float* __restrict__ off,
                          const float* __restrict__ wgt,
                          const float* __restrict__ bias,
                          float* __restrict__ out)
{
    // SoA layouts so stage-2 lanes (consecutive tap t) hit consecutive banks.
    __shared__ int   s_idx[8][NTAP];       // 8 corners x 216 taps, 6.9 KB
    __shared__ float s_w  [8][NTAP];       // 6.9 KB
    __shared__ float s_v  [NPOS][CK];      // 8 x 864 f32 = 27.6 KB

    const int tid   = threadIdx.x;
    const int blk   = blockIdx.x;
    const int n0    = blk * NPOS;          // global (b,n) base; N % NPOS == 0
    const int b     = n0 / N;
    const int nbase = n0 % N;

    // ---- stage 1: per-tap trilinear corner indices + weights ----
    for (int t = tid; t < NTAP; t += THREADS) {
        const int p = t / KN;
        const int k = t % KN;
        const int n = nbase + p;
        const int oz = n / (HO * WO);
        const int rr = n % (HO * WO);
        const int oy = rr / WO;
        const int ox = rr % WO;
        const int kz = k / 9;
        const int kr = k % 9;
        const int ky = kr / 3;
        const int kx = kr % 3;

        const float offz = off[((size_t)(b * 81 + k * 3 + 0)) * N + n];
        const float offy = off[((size_t)(b * 81 + k * 3 + 1)) * N + n];
        const float offx = off[((size_t)(b * 81 + k * 3 + 2)) * N + n];

        const float z  = (float)(oz - 1 + kz) + offz;
        const float y  = (float)(oy - 1 + ky) + offy;
        const float xx = (float)(ox - 1 + kx) + offx;

        const float z0f = floorf(z), y0f = floorf(y), x0f = floorf(xx);
        const float fz = z - z0f, fy = y - y0f, fx = xx - x0f;
        const int z0 = (int)z0f, y0 = (int)y0f, x0 = (int)x0f;

        #pragma unroll
        for (int cz = 0; cz < 2; ++cz) {
            const int   iz = z0 + cz;
            const float wz = cz ? fz : 1.0f - fz;
            #pragma unroll
            for (int cy = 0; cy < 2; ++cy) {
                const int   iy = y0 + cy;
                const float wy = cy ? fy : 1.0f - fy;
                #pragma unroll
                for (int cx = 0; cx < 2; ++cx) {
                    const int   ix = x0 + cx;
                    const float wx = cx ? fx : 1.0f - fx;
                    const bool valid = (iz >= 0) && (iz < D) &&
                                       (iy >= 0) && (iy < H) &&
                                       (ix >= 0) && (ix < W);
                    const int izc = min(max(iz, 0), D - 1);
                    const int iyc = min(max(iy, 0), H - 1);
                    const int ixc = min(max(ix, 0), W - 1);
                    const int corner = (cz * 2 + cy) * 2 + cx;
                    s_idx[corner][t] = (izc * H + iyc) * W + ixc;
                    s_w  [corner][t] = valid ? (wz * wy * wx) : 0.0f;
                }
            }
        }
    }
    __syncthreads();

    // ---- stage 2: gather sampled values into im2col columns in LDS ----
    for (int s = tid; s < NPOS * CK; s += THREADS) {
        const int k = s % KN;
        const int c = (s / KN) % C;
        const int p = s / (KN * C);
        const int t = p * KN + k;
        const float* xb = x + ((size_t)(b * C + c)) * (D * H * W);
        float acc = 0.0f;
        #pragma unroll
        for (int corner = 0; corner < 8; ++corner)
            acc += s_w[corner][t] * xb[s_idx[corner][t]];
        s_v[p][c * KN + k] = acc;
    }
    __syncthreads();

    // ---- stage 3: out[p][o] = bias[o] + W[o,:] . v[p,:] ----
    const int o  = tid & 63;      // output channel
    const int pg = tid >> 6;      // 0..3 -> positions pg and pg+4
    float acc0 = bias[o];
    float acc1 = acc0;
    const float* wrow = wgt + (size_t)o * CK;
    const float* v0 = s_v[pg];
    const float* v1 = s_v[pg + 4];
    #pragma unroll 4
    for (int ck = 0; ck < CK; ck += 4) {
        const float4 w4 = *reinterpret_cast<const float4*>(wrow + ck);
        acc0 += w4.x * v0[ck]     + w4.y * v0[ck + 1]
              + w4.z * v0[ck + 2] + w4.w * v0[ck + 3];
        acc1 += w4.x * v1[ck]     + w4.y * v1[ck + 1]
              + w4.z * v1[ck + 2] + w4.w * v1[ck + 3];
    }
    const int na = nbase + pg;
    const int nb = nbase + pg + 4;
    out[((size_t)(b * CO + o)) * N + na] = acc0;
    out[((size_t)(b * CO + o)) * N + nb] = acc1;
}

extern "C" void kernel_launch(void* const* d_in, const int* in_sizes, int n_in,
                              void* d_out, int out_size, void* d_ws, size_t ws_size,
                              hipStream_t stream) {
    const float* x    = (const float*)d_in[0];
    const float* off  = (const float*)d_in[1];
    const float* wgt  = (const float*)d_in[2];
    const float* bias = (const float*)d_in[3];
    float* out = (float*)d_out;

    deform_conv3d_kernel<<<NBLK, THREADS, 0, stream>>>(x, off, wgt, bias, out);
}

// Round 2
// 116.136 us; speedup vs baseline: 4.7106x; 4.7106x over previous
//
#include <hip/hip_runtime.h>
#include <hip/hip_bf16.h>

// DeformConv3d fixed geometry:
// x: (2,32,24,24,24) f32, offset: (2,81,24,24,24) f32,
// weight: (64,32,3,3,3) f32, bias: (64,) f32 -> out: (2,64,24,24,24) f32
// stride=1, pad=1, dil=1, groups=1, deform_groups=1
//
// Structure:
//  prep_x: x -> xT bf16 channel-last [b][voxel][32c] (1.77 MB in d_ws)
//          -> one trilinear corner = one 64B cache line.
//  prep_w: weight -> bf16 MFMA A-fragments, K-dim reordered as k'=ktap*?? :
//          k' = kstep*32 + c  (c fastest) so gather can write contiguous
//          32-channel columns to LDS. (110 KB in d_ws)
//  main:   448 thr/block, 16 output positions/block.
//          gather: 1 thread = 1 tap (432 taps), 32 fp32 accs, 8 corners,
//                  4x ds_write_b128 of bf16 column.
//          GEMM: 4 waves x (16o x 16pos), 27x mfma_f32_16x16x32_bf16.

constexpr int B   = 2;
constexpr int C   = 32;
constexpr int D   = 24, H = 24, W = 24;
constexpr int CO  = 64;
constexpr int KN  = 27;
constexpr int DHW = D * H * W;        // 13824
constexpr int N   = DHW;              // output positions per batch
constexpr int CK  = C * KN;           // 864

constexpr int NPOS     = 16;
constexpr int NTAP     = NPOS * KN;   // 432
constexpr int TPB_MAIN = 448;         // 7 waves; 4 do the GEMM
constexpr int PADR     = CK + 8;      // 872 bf16 per LDS row (bank-friendly)
constexpr int NBLK     = (B * N) / NPOS;  // 1728

using short8 = __attribute__((ext_vector_type(8))) short;
using f32x4  = __attribute__((ext_vector_type(4))) float;

__device__ __forceinline__ unsigned short f2bf(float f) {
    unsigned int u = __float_as_uint(f);
    unsigned int r = (u + 0x7FFFu + ((u >> 16) & 1u)) >> 16;  // RNE
    return (unsigned short)r;
}

// ---- prep 1: x (b,c,vox) f32 -> xT (b,vox,c) bf16 ----
__global__ __launch_bounds__(256)
void prep_x(const float* __restrict__ x, unsigned short* __restrict__ xT) {
    const int v   = blockIdx.x * 256 + threadIdx.x;   // 0 .. B*DHW-1
    const int b   = v / DHW;
    const int vox = v - b * DHW;
    int words[16];
    #pragma unroll
    for (int i = 0; i < 16; ++i) {
        const float f0 = x[((size_t)(b * C + 2 * i))     * DHW + vox];
        const float f1 = x[((size_t)(b * C + 2 * i + 1)) * DHW + vox];
        words[i] = (int)f2bf(f0) | ((int)f2bf(f1) << 16);
    }
    int4* dst = reinterpret_cast<int4*>(xT + (size_t)v * 32);
    dst[0] = make_int4(words[0],  words[1],  words[2],  words[3]);
    dst[1] = make_int4(words[4],  words[5],  words[6],  words[7]);
    dst[2] = make_int4(words[8],  words[9],  words[10], words[11]);
    dst[3] = make_int4(words[12], words[13], words[14], words[15]);
}

// ---- prep 2: weight f32 -> bf16 A-fragments ----
// A[m][k'] with m = o within tile, k' = kstep*32 + c.
// elem idx = ((otile*27 + kstep)*64 + lane)*8 + j
//   o = otile*16 + (lane&15), c = 8*(lane>>4) + j, ktap = kstep
__global__ __launch_bounds__(256)
void prep_w(const float* __restrict__ wgt, unsigned short* __restrict__ wp) {
    const int idx   = blockIdx.x * 256 + threadIdx.x;  // 0 .. 55295
    const int j     = idx & 7;
    const int lane  = (idx >> 3) & 63;
    const int t     = idx >> 9;          // otile*27 + kstep
    const int otile = t / 27;
    const int kstep = t - otile * 27;
    const int o     = otile * 16 + (lane & 15);
    const int c     = 8 * (lane >> 4) + j;
    wp[idx] = f2bf(wgt[(size_t)o * CK + c * KN + kstep]);
}

// ---- main fused kernel ----
__global__ __launch_bounds__(TPB_MAIN)
void deform_main(const float* __restrict__ off,
                 const unsigned short* __restrict__ xT,
                 const unsigned short* __restrict__ wp,
                 const float* __restrict__ bias,
                 float* __restrict__ out) {
    __shared__ unsigned short s_vb[NPOS * PADR];   // 27904 B

    const int tid   = threadIdx.x;
    const int blk   = blockIdx.x;
    const int n0    = blk * NPOS;
    const int b     = n0 / N;
    const int nbase = n0 - b * N;

    if (tid < NTAP) {
        const int p = tid & 15;
        const int k = tid >> 4;          // 0..26
        const int n = nbase + p;
        const int oz = n / 576;
        const int rr = n - oz * 576;
        const int oy = rr / 24;
        const int ox = rr - oy * 24;
        const int kz = k / 9;
        const int kr = k - kz * 9;
        const int ky = kr / 3;
        const int kx = kr - ky * 3;

        const float offz = off[((size_t)(b * 81 + k * 3 + 0)) * N + n];
        const float offy = off[((size_t)(b * 81 + k * 3 + 1)) * N + n];
        const float offx = off[((size_t)(b * 81 + k * 3 + 2)) * N + n];

        const float z  = (float)(oz - 1 + kz) + offz;
        const float y  = (float)(oy - 1 + ky) + offy;
        const float xx = (float)(ox - 1 + kx) + offx;
        const float zf = floorf(z), yf = floorf(y), xf = floorf(xx);
        const float fz = z - zf, fy = y - yf, fx = xx - xf;
        const int z0 = (int)zf, y0 = (int)yf, x0 = (int)xf;

        float acc[32];
        #pragma unroll
        for (int c = 0; c < 32; ++c) acc[c] = 0.0f;

        #pragma unroll
        for (int cz = 0; cz < 2; ++cz) {
            const int   iz = z0 + cz;
            const float wz = cz ? fz : 1.0f - fz;
            const bool  vz = (iz >= 0) && (iz < D);
            const int   izc = min(max(iz, 0), D - 1);
            #pragma unroll
            for (int cy = 0; cy < 2; ++cy) {
                const int   iy = y0 + cy;
                const float wy = cy ? fy : 1.0f - fy;
                const bool  vy = (iy >= 0) && (iy < H);
                const int   iyc = min(max(iy, 0), H - 1);
                #pragma unroll
                for (int cx = 0; cx < 2; ++cx) {
                    const int   ix = x0 + cx;
                    const float wx = cx ? fx : 1.0f - fx;
                    const bool  vd = vz && vy && (ix >= 0) && (ix < W);
                    const int   ixc = min(max(ix, 0), W - 1);
                    const float wc = vd ? (wz * wy * wx) : 0.0f;
                    const int4* src = reinterpret_cast<const int4*>(
                        xT + ((size_t)(b * DHW) + (izc * H + iyc) * W + ixc) * 32);
                    #pragma unroll
                    for (int q = 0; q < 4; ++q) {
                        const int4 dv = src[q];
                        const int w0 = dv.x, w1 = dv.y, w2 = dv.z, w3 = dv.w;
                        acc[q*8+0] += wc * __uint_as_float(((unsigned)w0) << 16);
                        acc[q*8+1] += wc * __uint_as_float(((unsigned)w0) & 0xFFFF0000u);
                        acc[q*8+2] += wc * __uint_as_float(((unsigned)w1) << 16);
                        acc[q*8+3] += wc * __uint_as_float(((unsigned)w1) & 0xFFFF0000u);
                        acc[q*8+4] += wc * __uint_as_float(((unsigned)w2) << 16);
                        acc[q*8+5] += wc * __uint_as_float(((unsigned)w2) & 0xFFFF0000u);
                        acc[q*8+6] += wc * __uint_as_float(((unsigned)w3) << 16);
                        acc[q*8+7] += wc * __uint_as_float(((unsigned)w3) & 0xFFFF0000u);
                    }
                }
            }
        }

        // store im2col column: s_vb[p][k*32 + c], contiguous 64 B
        int4* dst = reinterpret_cast<int4*>(&s_vb[p * PADR + k * 32]);
        #define PACK2(i) ((int)f2bf(acc[2*(i)]) | ((int)f2bf(acc[2*(i)+1]) << 16))
        dst[0] = make_int4(PACK2(0),  PACK2(1),  PACK2(2),  PACK2(3));
        dst[1] = make_int4(PACK2(4),  PACK2(5),  PACK2(6),  PACK2(7));
        dst[2] = make_int4(PACK2(8),  PACK2(9),  PACK2(10), PACK2(11));
        dst[3] = make_int4(PACK2(12), PACK2(13), PACK2(14), PACK2(15));
        #undef PACK2
    }
    __syncthreads();

    const int wv = tid >> 6;
    if (wv < 4) {
        const int lane = tid & 63;
        f32x4 acc4 = {0.f, 0.f, 0.f, 0.f};
        const short8* wrow = reinterpret_cast<const short8*>(wp) + (wv * 27) * 64 + lane;
        const int lrow = (lane & 15) * PADR;
        const int lcol = (lane >> 4) * 8;
        #pragma unroll
        for (int ks = 0; ks < 27; ++ks) {
            const short8 a = wrow[ks * 64];
            const short8 bf = *reinterpret_cast<const short8*>(&s_vb[lrow + ks * 32 + lcol]);
            acc4 = __builtin_amdgcn_mfma_f32_16x16x32_bf16(a, bf, acc4, 0, 0, 0);
        }
        // C/D: col = lane&15 (pos), row = (lane>>4)*4 + r (o within tile) [m89]
        const int p = lane & 15;
        const int n = nbase + p;
        const int obase = wv * 16 + (lane >> 4) * 4;
        #pragma unroll
        for (int r = 0; r < 4; ++r) {
            const int o = obase + r;
            out[((size_t)(b * CO + o)) * N + n] = acc4[r] + bias[o];
        }
    }
}

extern "C" void kernel_launch(void* const* d_in, const int* in_sizes, int n_in,
                              void* d_out, int out_size, void* d_ws, size_t ws_size,
                              hipStream_t stream) {
    const float* x    = (const float*)d_in[0];
    const float* off  = (const float*)d_in[1];
    const float* wgt  = (const float*)d_in[2];
    const float* bias = (const float*)d_in[3];
    float* out = (float*)d_out;

    unsigned short* xT = (unsigned short*)d_ws;                       // 1,769,472 B
    unsigned short* wp = (unsigned short*)((char*)d_ws + 1769472);    // 110,592 B

    prep_x<<<(B * DHW) / 256, 256, 0, stream>>>(x, xT);
    prep_w<<<(CO * CK) / 256, 256, 0, stream>>>(wgt, wp);
    deform_main<<<NBLK, TPB_MAIN, 0, stream>>>(off, xT, wp, bias, out);
}

// Round 3
// 109.910 us; speedup vs baseline: 4.9774x; 1.0566x over previous
//
#include <hip/hip_runtime.h>
#include <hip/hip_fp16.h>

// DeformConv3d fixed geometry:
// x: (2,32,24,24,24) f32, offset: (2,81,24,24,24) f32,
// weight: (64,32,3,3,3) f32, bias: (64,) f32 -> out: (2,64,24,24,24) f32
// stride=1, pad=1, dil=1, groups=1, deform_groups=1
//
// f16 pipeline:
//  prep_fused: (a) x -> xT f16 channel-last [b][voxel][32c]; 4 thr/voxel.
//              (b) weight -> f16 MFMA A-fragments, K reordered k'=kstep*32+c.
//  main: 448 thr/block, 16 positions/block.
//        gather: 1 thread = 1 tap; 8 corner (addr,w) precomputed, loads
//                batched 4-corners at a time, v_pk_fma_f16 accumulate,
//                acc regs stored directly as 4x ds_write_b128.
//        GEMM: 4 waves x (16o x 16pos), 27x mfma_f32_16x16x32_f16.

constexpr int B   = 2;
constexpr int C   = 32;
constexpr int D   = 24, H = 24, W = 24;
constexpr int CO  = 64;
constexpr int KN  = 27;
constexpr int DHW = D * H * W;        // 13824
constexpr int N   = DHW;
constexpr int CK  = C * KN;           // 864

constexpr int NPOS     = 16;
constexpr int NTAP     = NPOS * KN;   // 432
constexpr int TPB_MAIN = 448;         // 7 waves; 4 do the GEMM
constexpr int PADR     = CK + 8;      // 872 f16 per LDS row (16B-aligned rows)
constexpr int NBLK     = (B * N) / NPOS;  // 1728

constexpr int PREPX_BLKS = (B * DHW * 4) / 256;  // 432
constexpr int PREPW_BLKS = (CO * CK) / 256;      // 216

using h8v   = __attribute__((ext_vector_type(8))) _Float16;
using f32x4 = __attribute__((ext_vector_type(4))) float;

__device__ __forceinline__ h8v splat8(float w) {
    const _Float16 h = (_Float16)w;
    h8v r;
    #pragma unroll
    for (int i = 0; i < 8; ++i) r[i] = h;
    return r;
}

// ---- fused prep ----
__global__ __launch_bounds__(256)
void prep_fused(const float* __restrict__ x, const float* __restrict__ wgt,
                _Float16* __restrict__ xT, _Float16* __restrict__ wp) {
    const int bid = blockIdx.x;
    if (bid < PREPX_BLKS) {
        // x (b,c,vox) f32 -> xT (b,vox,c) f16 ; thread = (voxel, channel-quad)
        const int idx = bid * 256 + threadIdx.x;
        const int v   = idx >> 2;
        const int q   = idx & 3;
        const int b   = v / DHW;
        const int vox = v - b * DHW;
        const float* src = x + ((size_t)(b * C + q * 8)) * DHW + vox;
        _Float16 tmp[8];
        #pragma unroll
        for (int i = 0; i < 8; ++i) tmp[i] = (_Float16)src[(size_t)i * DHW];
        *reinterpret_cast<int4*>(xT + (size_t)v * 32 + q * 8) =
            *reinterpret_cast<const int4*>(tmp);
    } else {
        // weight f32 -> f16 A-fragments:
        // elem idx = ((otile*27 + kstep)*64 + lane)*8 + j
        //   o = otile*16 + (lane&15), c = 8*(lane>>4) + j
        const int idx   = (bid - PREPX_BLKS) * 256 + threadIdx.x;
        const int j     = idx & 7;
        const int lane  = (idx >> 3) & 63;
        const int t     = idx >> 9;
        const int otile = t / 27;
        const int kstep = t - otile * 27;
        const int o     = otile * 16 + (lane & 15);
        const int c     = 8 * (lane >> 4) + j;
        wp[idx] = (_Float16)wgt[(size_t)o * CK + c * KN + kstep];
    }
}

// ---- main fused kernel ----
__global__ __launch_bounds__(TPB_MAIN)
void deform_main(const float* __restrict__ off,
                 const _Float16* __restrict__ xT,
                 const _Float16* __restrict__ wp,
                 const float* __restrict__ bias,
                 float* __restrict__ out) {
    __shared__ _Float16 s_vb[NPOS * PADR];   // 27904 B

    const int tid   = threadIdx.x;
    const int blk   = blockIdx.x;
    const int n0    = blk * NPOS;
    const int b     = n0 / N;
    const int nbase = n0 - b * N;

    if (tid < NTAP) {
        const int p = tid & 15;
        const int k = tid >> 4;          // 0..26
        const int n = nbase + p;
        const int oz = n / 576;
        const int rr = n - oz * 576;
        const int oy = rr / 24;
        const int ox = rr - oy * 24;
        const int kz = k / 9;
        const int kr = k - kz * 9;
        const int ky = kr / 3;
        const int kx = kr - ky * 3;

        const float offz = off[((size_t)(b * 81 + k * 3 + 0)) * N + n];
        const float offy = off[((size_t)(b * 81 + k * 3 + 1)) * N + n];
        const float offx = off[((size_t)(b * 81 + k * 3 + 2)) * N + n];

        const float z  = (float)(oz - 1 + kz) + offz;
        const float y  = (float)(oy - 1 + ky) + offy;
        const float xx = (float)(ox - 1 + kx) + offx;
        const float zf = floorf(z), yf = floorf(y), xf = floorf(xx);
        const float fz = z - zf, fy = y - yf, fx = xx - xf;
        const int z0 = (int)zf, y0 = (int)yf, x0 = (int)xf;

        // all 8 corner (index, weight) pairs up front
        int   cidx[8];
        float cw[8];
        #pragma unroll
        for (int cr = 0; cr < 8; ++cr) {
            const int cz = cr >> 2, cy = (cr >> 1) & 1, cx = cr & 1;
            const int iz = z0 + cz, iy = y0 + cy, ix = x0 + cx;
            const bool vd = ((unsigned)iz < (unsigned)D) &&
                            ((unsigned)iy < (unsigned)H) &&
                            ((unsigned)ix < (unsigned)W);
            const int izc = min(max(iz, 0), D - 1);
            const int iyc = min(max(iy, 0), H - 1);
            const int ixc = min(max(ix, 0), W - 1);
            cidx[cr] = (izc * H + iyc) * W + ixc;
            const float wz = cz ? fz : 1.0f - fz;
            const float wy = cy ? fy : 1.0f - fy;
            const float wx = cx ? fx : 1.0f - fx;
            cw[cr] = vd ? (wz * wy * wx) : 0.0f;
        }

        h8v acc0 = splat8(0.0f), acc1 = splat8(0.0f),
            acc2 = splat8(0.0f), acc3 = splat8(0.0f);
        const h8v* base = reinterpret_cast<const h8v*>(xT) + (size_t)b * DHW * 4;

        // two batches of 4 corners: 16 loads issued, then 16 pk-FMAs
        #pragma unroll
        for (int hb = 0; hb < 2; ++hb) {
            h8v v[4][4];
            #pragma unroll
            for (int cr = 0; cr < 4; ++cr) {
                const h8v* s = base + (size_t)cidx[hb * 4 + cr] * 4;
                v[cr][0] = s[0]; v[cr][1] = s[1];
                v[cr][2] = s[2]; v[cr][3] = s[3];
            }
            #pragma unroll
            for (int cr = 0; cr < 4; ++cr) {
                const h8v w8 = splat8(cw[hb * 4 + cr]);
                acc0 += v[cr][0] * w8;
                acc1 += v[cr][1] * w8;
                acc2 += v[cr][2] * w8;
                acc3 += v[cr][3] * w8;
            }
        }

        // im2col column: s_vb[p][k*32 + c], contiguous 64 B
        h8v* dst = reinterpret_cast<h8v*>(&s_vb[p * PADR + k * 32]);
        dst[0] = acc0; dst[1] = acc1; dst[2] = acc2; dst[3] = acc3;
    }
    __syncthreads();

    const int wv = tid >> 6;
    if (wv < 4) {
        const int lane = tid & 63;
        f32x4 acc4 = {0.f, 0.f, 0.f, 0.f};
        const h8v* wrow = reinterpret_cast<const h8v*>(wp) + (wv * 27) * 64 + lane;
        const int lrow = (lane & 15) * PADR;
        const int lcol = (lane >> 4) * 8;
        #pragma unroll
        for (int ks = 0; ks < 27; ++ks) {
            const h8v a  = wrow[ks * 64];
            const h8v bf = *reinterpret_cast<const h8v*>(&s_vb[lrow + ks * 32 + lcol]);
            acc4 = __builtin_amdgcn_mfma_f32_16x16x32_f16(a, bf, acc4, 0, 0, 0);
        }
        // C/D: col = lane&15 (pos), row = (lane>>4)*4 + r (o within tile)
        const int p = lane & 15;
        const int n = nbase + p;
        const int obase = wv * 16 + (lane >> 4) * 4;
        #pragma unroll
        for (int r = 0; r < 4; ++r) {
            const int o = obase + r;
            out[((size_t)(b * CO + o)) * N + n] = acc4[r] + bias[o];
        }
    }
}

extern "C" void kernel_launch(void* const* d_in, const int* in_sizes, int n_in,
                              void* d_out, int out_size, void* d_ws, size_t ws_size,
                              hipStream_t stream) {
    const float* x    = (const float*)d_in[0];
    const float* off  = (const float*)d_in[1];
    const float* wgt  = (const float*)d_in[2];
    const float* bias = (const float*)d_in[3];
    float* out = (float*)d_out;

    _Float16* xT = (_Float16*)d_ws;                        // 1,769,472 B
    _Float16* wp = (_Float16*)((char*)d_ws + 1769472);     //   110,592 B

    prep_fused<<<PREPX_BLKS + PREPW_BLKS, 256, 0, stream>>>(x, wgt, xT, wp);
    deform_main<<<NBLK, TPB_MAIN, 0, stream>>>(off, xT, wp, bias, out);
}

// Round 4
// 100.083 us; speedup vs baseline: 5.4662x; 1.0982x over previous
//
#include <hip/hip_runtime.h>
#include <hip/hip_fp16.h>

// DeformConv3d fixed geometry:
// x: (2,32,24,24,24) f32, offset: (2,81,24,24,24) f32,
// weight: (64,32,3,3,3) f32, bias: (64,) f32 -> out: (2,64,24,24,24) f32
//
// f16 pipeline, quad-cooperative gather:
//  prep: (a) x -> xT f16 channel-last [b][voxel][32c] via LDS transpose
//            (coalesced loads, conflict-free LDS, contiguous 64B stores)
//        (b) weight -> f16 MFMA A-fragments, K reordered k'=kstep*32+c.
//  main: 576 thr (9 waves), 32 positions/block.
//        gather: task = (tap, chunk q); lanes of a quad read the 4
//                consecutive 16B chunks of ONE corner -> 1 line/quad.
//                6 tasks/thread, v_pk_fma_f16 accumulate, ds_write_b128.
//        GEMM: 8 waves x (16o x 16pos tile), 27x mfma_f32_16x16x32_f16.

constexpr int B   = 2;
constexpr int C   = 32;
constexpr int D   = 24, H = 24, W = 24;
constexpr int CO  = 64;
constexpr int KN  = 27;
constexpr int DHW = D * H * W;        // 13824
constexpr int N   = DHW;
constexpr int CK  = C * KN;           // 864

constexpr int NPOS     = 32;
constexpr int NTAP     = NPOS * KN;       // 864
constexpr int NTASK    = NTAP * 4;        // 3456
constexpr int TPB_MAIN = 576;             // 9 waves; NTASK/TPB = 6 exact
constexpr int PADR     = CK + 8;          // 872 f16 row; stride 1744B = 80 mod 128
constexpr int NBLK     = (B * N) / NPOS;  // 864

constexpr int PREPX_BLKS = (B * DHW) / 256;  // 108
constexpr int PREPW_BLKS = (CO * CK) / 256;  // 216

using h8v   = __attribute__((ext_vector_type(8))) _Float16;
using f32x4 = __attribute__((ext_vector_type(4))) float;

__device__ __forceinline__ h8v splat8(float w) {
    const _Float16 h = (_Float16)w;
    h8v r;
    #pragma unroll
    for (int i = 0; i < 8; ++i) r[i] = h;
    return r;
}

__device__ __forceinline__ unsigned pack2h(float a, float b) {
    const _Float16 ha = (_Float16)a, hb = (_Float16)b;
    unsigned short ua, ub;
    __builtin_memcpy(&ua, &ha, 2);
    __builtin_memcpy(&ub, &hb, 2);
    return (unsigned)ua | ((unsigned)ub << 16);
}

// ---- fused prep ----
__global__ __launch_bounds__(256)
void prep_fused(const float* __restrict__ x, const float* __restrict__ wgt,
                _Float16* __restrict__ xT, _Float16* __restrict__ wp) {
    const int bid = blockIdx.x;
    if (bid < PREPX_BLKS) {
        // transpose tile: 256 voxels x 32 channels. Rows of 21 u32 (odd
        // stride -> conflict-free u32 writes and b32 reads).
        __shared__ unsigned s_t[256 * 21];
        const int tid = threadIdx.x;
        const int v0  = bid * 256;             // blocks 0-53: b=0, 54-107: b=1
        const int b   = (v0 >= DHW) ? 1 : 0;
        const int vox = (v0 - b * DHW) + tid;
        const float* xb = x + (size_t)(b * C) * DHW + vox;
        #pragma unroll
        for (int c2 = 0; c2 < 16; ++c2) {
            const float f0 = xb[(size_t)(2 * c2)     * DHW];
            const float f1 = xb[(size_t)(2 * c2 + 1) * DHW];
            s_t[tid * 21 + c2] = pack2h(f0, f1);
        }
        __syncthreads();
        unsigned r[16];
        #pragma unroll
        for (int j = 0; j < 16; ++j) r[j] = s_t[tid * 21 + j];
        int4* dst = reinterpret_cast<int4*>(xT + ((size_t)(v0 + tid)) * 32);
        dst[0] = make_int4(r[0],  r[1],  r[2],  r[3]);
        dst[1] = make_int4(r[4],  r[5],  r[6],  r[7]);
        dst[2] = make_int4(r[8],  r[9],  r[10], r[11]);
        dst[3] = make_int4(r[12], r[13], r[14], r[15]);
    } else {
        // weight f32 -> f16 A-fragments:
        // elem idx = ((otile*27 + kstep)*64 + lane)*8 + j
        //   o = otile*16 + (lane&15), c = 8*(lane>>4) + j
        const int idx   = (bid - PREPX_BLKS) * 256 + threadIdx.x;
        const int j     = idx & 7;
        const int lane  = (idx >> 3) & 63;
        const int t     = idx >> 9;
        const int otile = t / 27;
        const int kstep = t - otile * 27;
        const int o     = otile * 16 + (lane & 15);
        const int c     = 8 * (lane >> 4) + j;
        wp[idx] = (_Float16)wgt[(size_t)o * CK + c * KN + kstep];
    }
}

// ---- main fused kernel ----
__global__ __launch_bounds__(TPB_MAIN, 5)
void deform_main(const float* __restrict__ off,
                 const _Float16* __restrict__ xT,
                 const _Float16* __restrict__ wp,
                 const float* __restrict__ bias,
                 float* __restrict__ out) {
    __shared__ _Float16 s_vb[NPOS * PADR];   // 55808 B

    const int tid   = threadIdx.x;
    const int blk   = blockIdx.x;
    const int n0    = blk * NPOS;
    const int b     = n0 / N;
    const int nbase = n0 - b * N;
    const h8v* xbase = reinterpret_cast<const h8v*>(xT) + (size_t)b * DHW * 4;
    const float* offb = off + (size_t)(b * 81) * N;

    #pragma unroll 1
    for (int r = 0; r < 6; ++r) {
        const int tau = tid + r * TPB_MAIN;
        const int q   = tau & 3;
        const int tap = tau >> 2;          // 0..863
        const int p   = tap & 31;
        const int k   = tap >> 5;          // 0..26
        const int n   = nbase + p;
        const int oz = n / 576;
        const int rr = n - oz * 576;
        const int oy = rr / 24;
        const int ox = rr - oy * 24;
        const int kz = k / 9;
        const int kr = k - kz * 9;
        const int ky = kr / 3;
        const int kx = kr - ky * 3;

        const float offz = offb[((size_t)(k * 3 + 0)) * N + n];
        const float offy = offb[((size_t)(k * 3 + 1)) * N + n];
        const float offx = offb[((size_t)(k * 3 + 2)) * N + n];

        const float z  = (float)(oz - 1 + kz) + offz;
        const float y  = (float)(oy - 1 + ky) + offy;
        const float xx = (float)(ox - 1 + kx) + offx;
        const float zf = floorf(z), yf = floorf(y), xf = floorf(xx);
        const float fz = z - zf, fy = y - yf, fx = xx - xf;
        const int z0 = (int)zf, y0 = (int)yf, x0 = (int)xf;

        int   cidx[8];
        float cw[8];
        #pragma unroll
        for (int cr = 0; cr < 8; ++cr) {
            const int cz = cr >> 2, cy = (cr >> 1) & 1, cx = cr & 1;
            const int iz = z0 + cz, iy = y0 + cy, ix = x0 + cx;
            const bool vd = ((unsigned)iz < (unsigned)D) &&
                            ((unsigned)iy < (unsigned)H) &&
                            ((unsigned)ix < (unsigned)W);
            const int izc = min(max(iz, 0), D - 1);
            const int iyc = min(max(iy, 0), H - 1);
            const int ixc = min(max(ix, 0), W - 1);
            cidx[cr] = (izc * H + iyc) * W + ixc;
            const float wz = cz ? fz : 1.0f - fz;
            const float wy = cy ? fy : 1.0f - fy;
            const float wx = cx ? fx : 1.0f - fx;
            cw[cr] = vd ? (wz * wy * wx) : 0.0f;
        }

        // quad-cooperative: this thread reads chunk q (channels 8q..8q+7)
        // of all 8 corners; lanes of a quad cover one 64B corner line.
        h8v v[8];
        #pragma unroll
        for (int cr = 0; cr < 8; ++cr)
            v[cr] = xbase[(size_t)cidx[cr] * 4 + q];
        h8v acc = splat8(0.0f);
        #pragma unroll
        for (int cr = 0; cr < 8; ++cr)
            acc += v[cr] * splat8(cw[cr]);

        *reinterpret_cast<h8v*>(&s_vb[p * PADR + k * 32 + q * 8]) = acc;
    }
    __syncthreads();

    const int wv = tid >> 6;
    if (wv < 8) {
        const int lane = tid & 63;
        const int ot   = wv & 3;       // o-tile
        const int pt   = wv >> 2;      // pos-tile
        const int p    = pt * 16 + (lane & 15);
        f32x4 acc4 = {0.f, 0.f, 0.f, 0.f};
        const h8v* wrow = reinterpret_cast<const h8v*>(wp) + (ot * 27) * 64 + lane;
        const int lrow = p * PADR;
        const int lcol = (lane >> 4) * 8;
        #pragma unroll
        for (int ks = 0; ks < 27; ++ks) {
            const h8v a  = wrow[ks * 64];
            const h8v bf = *reinterpret_cast<const h8v*>(&s_vb[lrow + ks * 32 + lcol]);
            acc4 = __builtin_amdgcn_mfma_f32_16x16x32_f16(a, bf, acc4, 0, 0, 0);
        }
        // C/D: col = lane&15 (pos-in-tile), row = (lane>>4)*4 + r (o-in-tile)
        const int n = nbase + p;
        const int obase = ot * 16 + (lane >> 4) * 4;
        #pragma unroll
        for (int rr = 0; rr < 4; ++rr) {
            const int o = obase + rr;
            out[((size_t)(b * CO + o)) * N + n] = acc4[rr] + bias[o];
        }
    }
}

extern "C" void kernel_launch(void* const* d_in, const int* in_sizes, int n_in,
                              void* d_out, int out_size, void* d_ws, size_t ws_size,
                              hipStream_t stream) {
    const float* x    = (const float*)d_in[0];
    const float* off  = (const float*)d_in[1];
    const float* wgt  = (const float*)d_in[2];
    const float* bias = (const float*)d_in[3];
    float* out = (float*)d_out;

    _Float16* xT = (_Float16*)d_ws;                        // 1,769,472 B
    _Float16* wp = (_Float16*)((char*)d_ws + 1769472);     //   110,592 B

    prep_fused<<<PREPX_BLKS + PREPW_BLKS, 256, 0, stream>>>(x, wgt, xT, wp);
    deform_main<<<NBLK, TPB_MAIN, 0, stream>>>(off, xT, wp, bias, out);
}